// Round 5
// baseline (271.789 us; speedup 1.0000x reference)
//
#include <hip/hip_runtime.h>
#include <hip/hip_bf16.h>

typedef __attribute__((ext_vector_type(8))) short short8;
typedef __attribute__((ext_vector_type(4))) short short4v;
typedef __attribute__((ext_vector_type(4))) float f32x4;

#define NPOS  65536
#define NOUT  16777216
#define QCAP  240
#define DELTA 0.05f

// ---------------------------------------------------------------------------
// Kernel 1: normalize prototypes (same reduce order as passing kernel),
// write pnN f32 [p][k] and bf16 copy pnBF [p][k].
// ---------------------------------------------------------------------------
__global__ __launch_bounds__(256) void proto_prep(
    const float* __restrict__ proto, float* __restrict__ pnN,
    ushort* __restrict__ pnBF) {
  int p = blockIdx.x;       // 0..511
  int c = threadIdx.x;      // 0..255
  float v = proto[p * 256 + c];
  float s = v * v;
  #pragma unroll
  for (int off = 32; off > 0; off >>= 1) s += __shfl_down(s, off);
  __shared__ float red[4];
  int lane = c & 63, wid = c >> 6;
  if (lane == 0) red[wid] = s;
  __syncthreads();
  float tot = red[0] + red[1] + red[2] + red[3];
  float nrm = fmaxf(sqrtf(tot), 1e-12f);
  float q = v / nrm;
  pnN[p * 256 + c] = q;
  __hip_bfloat16 h = __float2bfloat16(q);
  pnBF[p * 256 + c] = *reinterpret_cast<ushort*>(&h);
}

// ---------------------------------------------------------------------------
// Kernel 2: 64 positions x 512 protos per block, 512 threads (8 waves).
// Occupancy-focused rebuild of the validated round-3 kernel:
//  - LDS exactly 40 KB (xbf 32K + union{raw 8K | post-staging scratch})
//    -> 4 blocks/CU target.
//  - acc[1][4] (16 regs) via 4 sequential m-quarters -> VGPR<=64 target
//    (8 waves/SIMD). Same bf16-score + global-max-DELTA candidate semantics,
//    exact fp32 rescore identical to the passing kernel.
//  - staging via global_load_lds width-16 (8 phases of 32 k-rows).
// ---------------------------------------------------------------------------
__global__ __launch_bounds__(512, 8) void match_kernel(
    const float* __restrict__ x, const float* __restrict__ proto,
    const float* __restrict__ pnN, const ushort* __restrict__ pnBF,
    float* __restrict__ out) {
  __shared__ __align__(16) ushort xbf[64 * 256];   // 32 KB bf16 [m][k] swizzled
  __shared__ __align__(16) union UU {
    float raw[32 * 64];                            // 8 KB f32 staging (per phase)
    struct {
      float wmax[8][16];
      float thr[16];
      int   queue[QCAP];
      float qscore[QCAP];
      int   idxl[64];
      int   qn;
    } s;
  } u;

  const int t = threadIdx.x;
  const int l = t & 63, w = t >> 6;
  const int g = l >> 4, c16 = l & 15, r8 = l & 7;
  const int n0 = blockIdx.x << 6;
  const int b = n0 >> 10, hw0 = n0 & 1023;
  const float* xg = x + ((size_t)b << 18) + hw0;   // + k*1024 + pos

  // ---- staging: 8 phases x 32 k-rows: global -> raw(f32) -> xbf(bf16) ----
  #pragma unroll 1
  for (int p = 0; p < 8; ++p) {
    {
      // wave w stages rows p*32 + w*4 .. +3 with one width-16 load:
      // lds dest raw[w*256 + lane*4] == raw[(w*4 + l>>4)*64 + (l&15)*4]
      const float* src =
          xg + ((((p << 5) + (w << 2) + (l >> 4)) << 10)) + ((l & 15) << 2);
      float* dst = &u.raw[w << 8];
      __builtin_amdgcn_global_load_lds(
          (const __attribute__((address_space(1))) unsigned int*)src,
          (__attribute__((address_space(3))) unsigned int*)dst, 16, 0, 0);
    }
    __syncthreads();
    {
      int m = t & 63, c4 = t >> 6;       // c4: which 4-k quad of the 32 rows
      short4v q;
      #pragma unroll
      for (int j = 0; j < 4; ++j) {
        float v = u.raw[(((c4 << 2) + j) << 6) + m];
        __hip_bfloat16 h = __float2bfloat16(v);
        q[j] = *reinterpret_cast<short*>(&h);
      }
      int chunk = (p << 2) + (c4 >> 1);  // absolute 16B (8-k) chunk 0..31
      int dst = (m << 8) + ((chunk ^ (m & 7)) << 3) + ((c4 & 1) << 2);
      *reinterpret_cast<short4v*>(&xbf[dst]) = q;
    }
    __syncthreads();
  }

  if (t == 0) u.s.qn = 0;   // visible before first flag (>=2 barriers away)

  const ushort* pB0 = pnBF + (((w << 6) + c16) << 8) + (g << 3);

  // ---- 4 m-quarters of 16 positions each ----
  #pragma unroll 1
  for (int mq = 0; mq < 4; ++mq) {
    f32x4 acc[4];
    #pragma unroll
    for (int ni = 0; ni < 4; ++ni) acc[ni] = (f32x4){0.f, 0.f, 0.f, 0.f};

    #pragma unroll
    for (int ks = 0; ks < 8; ++ks) {
      const short8 a = *reinterpret_cast<const short8*>(
          &xbf[(((mq << 4) + c16) << 8) + ((((ks << 2) + g) ^ r8) << 3)]);
      #pragma unroll
      for (int ni = 0; ni < 4; ++ni) {
        const short8 bf = *reinterpret_cast<const short8*>(
            pB0 + (ni << 12) + (ks << 5));
        acc[ni] = __builtin_amdgcn_mfma_f32_16x16x32_bf16(a, bf, acc[ni], 0, 0, 0);
      }
    }

    // per-pos max over 512 protos: reg-reduce + 16-lane shfl + 8-wave merge
    // D layout: pos row (within 16) = g*4 + r, proto col = ni*16 + c16
    #pragma unroll
    for (int r = 0; r < 4; ++r) {
      float v = fmaxf(fmaxf(acc[0][r], acc[1][r]), fmaxf(acc[2][r], acc[3][r]));
      #pragma unroll
      for (int s = 1; s < 16; s <<= 1) v = fmaxf(v, __shfl_xor(v, s));
      if (c16 == 0) u.s.wmax[w][(g << 2) + r] = v;
    }
    __syncthreads();
    if (t < 16) {
      float bm = u.s.wmax[0][t];
      #pragma unroll
      for (int ww = 1; ww < 8; ++ww) bm = fmaxf(bm, u.s.wmax[ww][t]);
      u.s.thr[t] = bm - DELTA;
    }
    __syncthreads();
    #pragma unroll
    for (int ni = 0; ni < 4; ++ni)
      #pragma unroll
      for (int r = 0; r < 4; ++r) {
        int p16 = (g << 2) + r;
        if (acc[ni][r] >= u.s.thr[p16]) {
          int slot = atomicAdd(&u.s.qn, 1);
          if (slot < QCAP)
            u.s.queue[slot] =
                (((w << 6) + (ni << 4) + c16) << 6) | ((mq << 4) + p16);
        }
      }
    __syncthreads();   // protects wmax/thr reuse next mq
  }

  // ---- exact fp32 rescore (identical arithmetic to the passing kernel) ----
  int n = u.s.qn < QCAP ? u.s.qn : QCAP;
  for (int j = t; j < n; j += 512) {
    int e = u.s.queue[j];
    int pos = e & 63, p = e >> 6;
    float a = 0.f;
    const float* pr = pnN + (p << 8);
    for (int k = 0; k < 256; ++k)
      a = fmaf(xg[(k << 10) + pos], pr[k], a);
    u.s.qscore[j] = a;
  }
  __syncthreads();

  // ---- final argmax per position (lowest index tie-break) ----
  if (t < 64) {
    float best = -3.4e38f;
    int bp = 1 << 30;
    for (int j = 0; j < n; ++j) {
      if ((u.s.queue[j] & 63) == t) {
        float s = u.s.qscore[j];
        int p = u.s.queue[j] >> 6;
        if (s > best || (s == best && p < bp)) { best = s; bp = p; }
      }
    }
    u.s.idxl[t] = bp;
    out[(size_t)NOUT + n0 + t] = (float)bp;
  }
  __syncthreads();

  // ---- recon gather: out[b][c][hw0+pos] = proto[idx[pos]][c] ----
  float* rb = out + ((size_t)b << 18) + hw0;
  #pragma unroll 1
  for (int it = 0; it < 32; ++it) {
    int lin = (it << 9) + t;
    int c = lin >> 6, pos = lin & 63;
    rb[((size_t)c << 10) + pos] = proto[(u.s.idxl[pos] << 8) + c];
  }
}

extern "C" void kernel_launch(void* const* d_in, const int* in_sizes, int n_in,
                              void* d_out, int out_size, void* d_ws, size_t ws_size,
                              hipStream_t stream) {
  const float* x = (const float*)d_in[0];        // (64, 256, 32, 32) f32
  const float* proto = (const float*)d_in[1];    // (512, 256) f32
  float* out = (float*)d_out;                    // 16777216 recon + 65536 idx
  float* pnN = (float*)d_ws;                     // 512*256 f32 = 512 KB
  ushort* pnBF = (ushort*)((char*)d_ws + 512 * 256 * sizeof(float)); // 256 KB

  proto_prep<<<512, 256, 0, stream>>>(proto, pnN, pnBF);
  match_kernel<<<NPOS / 64, 512, 0, stream>>>(x, proto, pnN, pnBF, out);
}

// Round 6
// 240.492 us; speedup vs baseline: 1.1301x; 1.1301x over previous
//
#include <hip/hip_runtime.h>
#include <hip/hip_bf16.h>

typedef __attribute__((ext_vector_type(8))) short short8;
typedef __attribute__((ext_vector_type(4))) short short4v;
typedef __attribute__((ext_vector_type(4))) float f32x4;

#define NPOS  65536
#define NOUT  16777216
#define QCAP  240
#define DELTA 0.05f

// ---------------------------------------------------------------------------
// Kernel 1: normalize prototypes, write pnN f32 [p][k] and bf16 copy.
// ---------------------------------------------------------------------------
__global__ __launch_bounds__(256) void proto_prep(
    const float* __restrict__ proto, float* __restrict__ pnN,
    ushort* __restrict__ pnBF) {
  int p = blockIdx.x;       // 0..511
  int c = threadIdx.x;      // 0..255
  float v = proto[p * 256 + c];
  float s = v * v;
  #pragma unroll
  for (int off = 32; off > 0; off >>= 1) s += __shfl_down(s, off);
  __shared__ float red[4];
  int lane = c & 63, wid = c >> 6;
  if (lane == 0) red[wid] = s;
  __syncthreads();
  float tot = red[0] + red[1] + red[2] + red[3];
  float nrm = fmaxf(sqrtf(tot), 1e-12f);
  float q = v / nrm;
  pnN[p * 256 + c] = q;
  __hip_bfloat16 h = __float2bfloat16(q);
  pnBF[p * 256 + c] = *reinterpret_cast<ushort*>(&h);
}

// ---------------------------------------------------------------------------
// Kernel 2: round-5 structure (PASSED, absmax 0) with two fixes:
//  - __launch_bounds__(512,6): reg budget ~85 (round-5's (512,8) forced
//    VGPR=32 -> scratch spills -> +690 MB traffic, 272 us).
//  - cnt[64]: positions with exactly 1 candidate skip fp32 rescore
//    (single candidate == argmax by the same DELTA-bound; ~94% of positions).
// ---------------------------------------------------------------------------
__global__ __launch_bounds__(512, 6) void match_kernel(
    const float* __restrict__ x, const float* __restrict__ proto,
    const float* __restrict__ pnN, const ushort* __restrict__ pnBF,
    float* __restrict__ out) {
  __shared__ __align__(16) ushort xbf[64 * 256];   // 32 KB bf16 [m][k] swizzled
  __shared__ __align__(16) union UU {
    float raw[32 * 64];                            // 8 KB f32 staging (per phase)
    struct {
      float wmax[8][16];
      float thr[16];
      int   queue[QCAP];
      float qscore[QCAP];
      int   idxl[64];
      int   cnt[64];
      int   qn;
    } s;
  } u;

  const int t = threadIdx.x;
  const int l = t & 63, w = t >> 6;
  const int g = l >> 4, c16 = l & 15, r8 = l & 7;
  const int n0 = blockIdx.x << 6;
  const int b = n0 >> 10, hw0 = n0 & 1023;
  const float* xg = x + ((size_t)b << 18) + hw0;   // + k*1024 + pos

  // ---- staging: 8 phases x 32 k-rows: global -> raw(f32) -> xbf(bf16) ----
  #pragma unroll 1
  for (int p = 0; p < 8; ++p) {
    {
      const float* src =
          xg + ((((p << 5) + (w << 2) + (l >> 4)) << 10)) + ((l & 15) << 2);
      float* dst = &u.raw[w << 8];
      __builtin_amdgcn_global_load_lds(
          (const __attribute__((address_space(1))) unsigned int*)src,
          (__attribute__((address_space(3))) unsigned int*)dst, 16, 0, 0);
    }
    __syncthreads();
    {
      int m = t & 63, c4 = t >> 6;       // c4: which 4-k quad of the 32 rows
      short4v q;
      #pragma unroll
      for (int j = 0; j < 4; ++j) {
        float v = u.raw[(((c4 << 2) + j) << 6) + m];
        __hip_bfloat16 h = __float2bfloat16(v);
        q[j] = *reinterpret_cast<short*>(&h);
      }
      int chunk = (p << 2) + (c4 >> 1);  // absolute 16B (8-k) chunk 0..31
      int dst = (m << 8) + ((chunk ^ (m & 7)) << 3) + ((c4 & 1) << 2);
      *reinterpret_cast<short4v*>(&xbf[dst]) = q;
    }
    __syncthreads();
  }

  if (t == 0) u.s.qn = 0;
  if (t < 64) u.s.cnt[t] = 0;   // safe: >=2 barriers before first use

  const ushort* pB0 = pnBF + (((w << 6) + c16) << 8) + (g << 3);

  // ---- 4 m-quarters of 16 positions each ----
  #pragma unroll 1
  for (int mq = 0; mq < 4; ++mq) {
    f32x4 acc[4];
    #pragma unroll
    for (int ni = 0; ni < 4; ++ni) acc[ni] = (f32x4){0.f, 0.f, 0.f, 0.f};

    #pragma unroll
    for (int ks = 0; ks < 8; ++ks) {
      const short8 a = *reinterpret_cast<const short8*>(
          &xbf[(((mq << 4) + c16) << 8) + ((((ks << 2) + g) ^ r8) << 3)]);
      #pragma unroll
      for (int ni = 0; ni < 4; ++ni) {
        const short8 bf = *reinterpret_cast<const short8*>(
            pB0 + (ni << 12) + (ks << 5));
        acc[ni] = __builtin_amdgcn_mfma_f32_16x16x32_bf16(a, bf, acc[ni], 0, 0, 0);
      }
    }

    // per-pos max over 512 protos
    #pragma unroll
    for (int r = 0; r < 4; ++r) {
      float v = fmaxf(fmaxf(acc[0][r], acc[1][r]), fmaxf(acc[2][r], acc[3][r]));
      #pragma unroll
      for (int s = 1; s < 16; s <<= 1) v = fmaxf(v, __shfl_xor(v, s));
      if (c16 == 0) u.s.wmax[w][(g << 2) + r] = v;
    }
    __syncthreads();
    if (t < 16) {
      float bm = u.s.wmax[0][t];
      #pragma unroll
      for (int ww = 1; ww < 8; ++ww) bm = fmaxf(bm, u.s.wmax[ww][t]);
      u.s.thr[t] = bm - DELTA;
    }
    __syncthreads();
    #pragma unroll
    for (int ni = 0; ni < 4; ++ni)
      #pragma unroll
      for (int r = 0; r < 4; ++r) {
        int p16 = (g << 2) + r;
        if (acc[ni][r] >= u.s.thr[p16]) {
          int pos = (mq << 4) + p16;
          int slot = atomicAdd(&u.s.qn, 1);
          atomicAdd(&u.s.cnt[pos], 1);
          if (slot < QCAP)
            u.s.queue[slot] = (((w << 6) + (ni << 4) + c16) << 6) | pos;
        }
      }
    __syncthreads();   // protects wmax/thr reuse next mq
  }

  // ---- exact fp32 rescore, only for positions with >=2 candidates ----
  int n = u.s.qn < QCAP ? u.s.qn : QCAP;
  for (int j = t; j < n; j += 512) {
    int e = u.s.queue[j];
    int pos = e & 63, p = e >> 6;
    if (u.s.cnt[pos] > 1) {
      float a = 0.f;
      const float* pr = pnN + (p << 8);
      for (int k = 0; k < 256; ++k)
        a = fmaf(xg[(k << 10) + pos], pr[k], a);
      u.s.qscore[j] = a;
    }
  }
  __syncthreads();

  // ---- final argmax per position (lowest index tie-break) ----
  if (t < 64) {
    int bp = 1 << 30;
    if (u.s.cnt[t] <= 1) {
      for (int j = 0; j < n; ++j)
        if ((u.s.queue[j] & 63) == t) { bp = u.s.queue[j] >> 6; break; }
    } else {
      float best = -3.4e38f;
      for (int j = 0; j < n; ++j) {
        if ((u.s.queue[j] & 63) == t) {
          float s = u.s.qscore[j];
          int p = u.s.queue[j] >> 6;
          if (s > best || (s == best && p < bp)) { best = s; bp = p; }
        }
      }
    }
    u.s.idxl[t] = bp;
    out[(size_t)NOUT + n0 + t] = (float)bp;
  }
  __syncthreads();

  // ---- recon gather: out[b][c][hw0+pos] = proto[idx[pos]][c] ----
  float* rb = out + ((size_t)b << 18) + hw0;
  #pragma unroll 1
  for (int it = 0; it < 32; ++it) {
    int lin = (it << 9) + t;
    int c = lin >> 6, pos = lin & 63;
    rb[((size_t)c << 10) + pos] = proto[(u.s.idxl[pos] << 8) + c];
  }
}

extern "C" void kernel_launch(void* const* d_in, const int* in_sizes, int n_in,
                              void* d_out, int out_size, void* d_ws, size_t ws_size,
                              hipStream_t stream) {
  const float* x = (const float*)d_in[0];        // (64, 256, 32, 32) f32
  const float* proto = (const float*)d_in[1];    // (512, 256) f32
  float* out = (float*)d_out;                    // 16777216 recon + 65536 idx
  float* pnN = (float*)d_ws;                     // 512*256 f32 = 512 KB
  ushort* pnBF = (ushort*)((char*)d_ws + 512 * 256 * sizeof(float)); // 256 KB

  proto_prep<<<512, 256, 0, stream>>>(proto, pnN, pnBF);
  match_kernel<<<NPOS / 64, 512, 0, stream>>>(x, proto, pnN, pnBF, out);
}

// Round 7
// 160.043 us; speedup vs baseline: 1.6982x; 1.5027x over previous
//
#include <hip/hip_runtime.h>
#include <hip/hip_bf16.h>

typedef __attribute__((ext_vector_type(8))) short short8;
typedef __attribute__((ext_vector_type(4))) short short4v;
typedef __attribute__((ext_vector_type(4))) float f32x4;

#define NPOS  65536
#define NOUT  16777216
#define QCAP  240
#define DELTA 0.05f

// ---------------------------------------------------------------------------
// Kernel 1: normalize prototypes, write pnN f32 [p][k] and bf16 copy.
// ---------------------------------------------------------------------------
__global__ __launch_bounds__(256) void proto_prep(
    const float* __restrict__ proto, float* __restrict__ pnN,
    ushort* __restrict__ pnBF) {
  int p = blockIdx.x;       // 0..511
  int c = threadIdx.x;      // 0..255
  float v = proto[p * 256 + c];
  float s = v * v;
  #pragma unroll
  for (int off = 32; off > 0; off >>= 1) s += __shfl_down(s, off);
  __shared__ float red[4];
  int lane = c & 63, wid = c >> 6;
  if (lane == 0) red[wid] = s;
  __syncthreads();
  float tot = red[0] + red[1] + red[2] + red[3];
  float nrm = fmaxf(sqrtf(tot), 1e-12f);
  float q = v / nrm;
  pnN[p * 256 + c] = q;
  __hip_bfloat16 h = __float2bfloat16(q);
  pnBF[p * 256 + c] = *reinterpret_cast<ushort*>(&h);
}

// ---------------------------------------------------------------------------
// Kernel 2: round-6 structure, two fixes:
//  - __launch_bounds__(512,3): arg2 is min BLOCKS/CU (CUDA semantics on this
//    toolchain; evidence: (512,4)->64, (512,6)->40, (512,8)->32 = 512/(2*arg2)).
//    Cap 85 >= need ~56 -> no spills; LDS 40KB allows up to 4 blocks/CU.
//  - serial argmax scans replaced by direct write (cnt==1) + packed 64-bit
//    LDS atomicMax (cnt>1), preserving exact-score lowest-p tie-break.
// ---------------------------------------------------------------------------
__global__ __launch_bounds__(512, 3) void match_kernel(
    const float* __restrict__ x, const float* __restrict__ proto,
    const float* __restrict__ pnN, const ushort* __restrict__ pnBF,
    float* __restrict__ out) {
  __shared__ __align__(16) ushort xbf[64 * 256];   // 32 KB bf16 [m][k] swizzled
  __shared__ __align__(16) union UU {
    float raw[32 * 64];                            // 8 KB f32 staging (per phase)
    struct {
      float wmax[8][16];
      float thr[16];
      int   queue[QCAP];
      unsigned long long b64[64];
      int   idxl[64];
      int   cnt[64];
      int   qn;
    } s;
  } u;

  const int t = threadIdx.x;
  const int l = t & 63, w = t >> 6;
  const int g = l >> 4, c16 = l & 15, r8 = l & 7;
  const int n0 = blockIdx.x << 6;
  const int b = n0 >> 10, hw0 = n0 & 1023;
  const float* xg = x + ((size_t)b << 18) + hw0;   // + k*1024 + pos

  // ---- staging: 8 phases x 32 k-rows: global -> raw(f32) -> xbf(bf16) ----
  #pragma unroll 1
  for (int p = 0; p < 8; ++p) {
    {
      const float* src =
          xg + ((((p << 5) + (w << 2) + (l >> 4)) << 10)) + ((l & 15) << 2);
      float* dst = &u.raw[w << 8];
      __builtin_amdgcn_global_load_lds(
          (const __attribute__((address_space(1))) unsigned int*)src,
          (__attribute__((address_space(3))) unsigned int*)dst, 16, 0, 0);
    }
    __syncthreads();
    {
      int m = t & 63, c4 = t >> 6;       // c4: which 4-k quad of the 32 rows
      short4v q;
      #pragma unroll
      for (int j = 0; j < 4; ++j) {
        float v = u.raw[(((c4 << 2) + j) << 6) + m];
        __hip_bfloat16 h = __float2bfloat16(v);
        q[j] = *reinterpret_cast<short*>(&h);
      }
      int chunk = (p << 2) + (c4 >> 1);  // absolute 16B (8-k) chunk 0..31
      int dst = (m << 8) + ((chunk ^ (m & 7)) << 3) + ((c4 & 1) << 2);
      *reinterpret_cast<short4v*>(&xbf[dst]) = q;
    }
    __syncthreads();
  }

  if (t == 0) u.s.qn = 0;
  if (t < 64) { u.s.cnt[t] = 0; u.s.b64[t] = 0ULL; }  // barrier-protected below

  const ushort* pB0 = pnBF + (((w << 6) + c16) << 8) + (g << 3);

  // ---- 4 m-quarters of 16 positions each ----
  #pragma unroll 1
  for (int mq = 0; mq < 4; ++mq) {
    f32x4 acc[4];
    #pragma unroll
    for (int ni = 0; ni < 4; ++ni) acc[ni] = (f32x4){0.f, 0.f, 0.f, 0.f};

    #pragma unroll
    for (int ks = 0; ks < 8; ++ks) {
      const short8 a = *reinterpret_cast<const short8*>(
          &xbf[(((mq << 4) + c16) << 8) + ((((ks << 2) + g) ^ r8) << 3)]);
      #pragma unroll
      for (int ni = 0; ni < 4; ++ni) {
        const short8 bf = *reinterpret_cast<const short8*>(
            pB0 + (ni << 12) + (ks << 5));
        acc[ni] = __builtin_amdgcn_mfma_f32_16x16x32_bf16(a, bf, acc[ni], 0, 0, 0);
      }
    }

    // per-pos max over 512 protos
    #pragma unroll
    for (int r = 0; r < 4; ++r) {
      float v = fmaxf(fmaxf(acc[0][r], acc[1][r]), fmaxf(acc[2][r], acc[3][r]));
      #pragma unroll
      for (int s = 1; s < 16; s <<= 1) v = fmaxf(v, __shfl_xor(v, s));
      if (c16 == 0) u.s.wmax[w][(g << 2) + r] = v;
    }
    __syncthreads();
    if (t < 16) {
      float bm = u.s.wmax[0][t];
      #pragma unroll
      for (int ww = 1; ww < 8; ++ww) bm = fmaxf(bm, u.s.wmax[ww][t]);
      u.s.thr[t] = bm - DELTA;
    }
    __syncthreads();
    #pragma unroll
    for (int ni = 0; ni < 4; ++ni)
      #pragma unroll
      for (int r = 0; r < 4; ++r) {
        int p16 = (g << 2) + r;
        if (acc[ni][r] >= u.s.thr[p16]) {
          int pos = (mq << 4) + p16;
          int slot = atomicAdd(&u.s.qn, 1);
          atomicAdd(&u.s.cnt[pos], 1);
          if (slot < QCAP)
            u.s.queue[slot] = (((w << 6) + (ni << 4) + c16) << 6) | pos;
        }
      }
    __syncthreads();   // protects wmax/thr reuse next mq
  }

  // ---- resolve: cnt==1 -> direct; cnt>1 -> exact fp32 rescore + atomicMax --
  int n = u.s.qn < QCAP ? u.s.qn : QCAP;
  for (int j = t; j < n; j += 512) {
    int e = u.s.queue[j];
    int pos = e & 63, p = e >> 6;
    if (u.s.cnt[pos] == 1) {
      u.s.idxl[pos] = p;               // sole candidate == argmax
    } else {
      float a = 0.f;                   // exact sequential fmaf (validated)
      const float* pr = pnN + (p << 8);
      for (int k = 0; k < 256; ++k)
        a = fmaf(xg[(k << 10) + pos], pr[k], a);
      unsigned int ub = __float_as_uint(a);
      ub ^= (unsigned int)(((int)ub >> 31)) | 0x80000000u;  // orderable
      unsigned long long key =
          ((unsigned long long)ub << 32) | (unsigned long long)(511 - p);
      atomicMax(&u.s.b64[pos], key);   // ties: larger (511-p) => smaller p
    }
  }
  __syncthreads();

  // ---- write indices ----
  if (t < 64) {
    int bp = (u.s.cnt[t] == 1) ? u.s.idxl[t]
                               : 511 - (int)(u.s.b64[t] & 511ULL);
    u.s.idxl[t] = bp;
    out[(size_t)NOUT + n0 + t] = (float)bp;
  }
  __syncthreads();

  // ---- recon gather: out[b][c][hw0+pos] = proto[idx[pos]][c] ----
  float* rb = out + ((size_t)b << 18) + hw0;
  #pragma unroll 1
  for (int it = 0; it < 32; ++it) {
    int lin = (it << 9) + t;
    int c = lin >> 6, pos = lin & 63;
    rb[((size_t)c << 10) + pos] = proto[(u.s.idxl[pos] << 8) + c];
  }
}

extern "C" void kernel_launch(void* const* d_in, const int* in_sizes, int n_in,
                              void* d_out, int out_size, void* d_ws, size_t ws_size,
                              hipStream_t stream) {
  const float* x = (const float*)d_in[0];        // (64, 256, 32, 32) f32
  const float* proto = (const float*)d_in[1];    // (512, 256) f32
  float* out = (float*)d_out;                    // 16777216 recon + 65536 idx
  float* pnN = (float*)d_ws;                     // 512*256 f32 = 512 KB
  ushort* pnBF = (ushort*)((char*)d_ws + 512 * 256 * sizeof(float)); // 256 KB

  proto_prep<<<512, 256, 0, stream>>>(proto, pnN, pnBF);
  match_kernel<<<NPOS / 64, 512, 0, stream>>>(x, proto, pnN, pnBF, out);
}